// Round 4
// baseline (690.229 us; speedup 1.0000x reference)
//
#include <hip/hip_runtime.h>
#include <math.h>

#define NN    50000
#define FDIM  200
#define E1N   400000
#define E2N   100000
#define EN    500000

typedef __attribute__((ext_vector_type(8))) short short8;
typedef __attribute__((ext_vector_type(4))) float f32x4;

// ---------------- workspace layout (4B units) ----------------
#define VALL_OFF   0            // 600 f
#define WALL_OFF   608          // 600 f
#define SCAL_OFF   1216         // NN*4 f = 200,000
#define RS_OFF     201216       // NN f
#define CNT_OFF    251216       // NN int (zeroed)
#define FILL_OFF   301216       // NN int (zeroed, then = offsets)
#define INCL_OFF   351216       // NN int (offsets)
#define BSUM_OFF   401216       // 256 int
#define SORT_OFF   401472       // EN int4 = 2,000,000 ints
#define XB_OFF     2401472      // NN*200 bf16 = 10,000,000 ushort = 5,000,000 f
#define AB_OFF     7401472      // 200*600 bf16 = 120,000 ushort = 60,000 f
#define TSB_OFF    7461472      // NN*400 bf16 = 20,000,000 ushort = 10,000,000 f
// total 17,461,472 floats = ~70 MB

static __device__ __forceinline__ unsigned short f2bf(float f) {
    unsigned int u = __float_as_uint(f);
    unsigned int r = (u + 0x7fffu + ((u >> 16) & 1u)) >> 16;
    return (unsigned short)r;
}
static __device__ __forceinline__ float bf2f(unsigned short s) {
    return __uint_as_float((unsigned int)s << 16);
}

// ---- DPP wave-64 sum (VALU-latency, 6 steps); result broadcast via readlane 63 ----
#define DPP_ADD(x, ctrl, rmask) \
    x += __int_as_float(__builtin_amdgcn_update_dpp(0, __float_as_int(x), ctrl, rmask, 0xf, true))

static __device__ __forceinline__ float wave_sum_bcast(float x) {
    DPP_ADD(x, 0x111, 0xf);   // row_shr:1
    DPP_ADD(x, 0x112, 0xf);   // row_shr:2
    DPP_ADD(x, 0x114, 0xf);   // row_shr:4
    DPP_ADD(x, 0x118, 0xf);   // row_shr:8
    DPP_ADD(x, 0x142, 0xa);   // row_bcast:15 -> rows 1,3
    DPP_ADD(x, 0x143, 0xc);   // row_bcast:31 -> rows 2,3
    return __int_as_float(__builtin_amdgcn_readlane(__float_as_int(x), 63));
}

static __device__ __forceinline__ float readlane_f(float v, int l) {
    return __int_as_float(__builtin_amdgcn_readlane(__float_as_int(v), l));
}

__global__ void k_coeffs(const float* __restrict__ a, const float* __restrict__ a2,
                         const float* __restrict__ mlpw,
                         float* __restrict__ vall, float* __restrict__ wall) {
    int k = blockIdx.x * blockDim.x + threadIdx.x;
    if (k >= 600) return;
    float v = 0.f, w = 0.f;
    for (int o = 0; o < FDIM; ++o) {
        float av = a[o * 600 + k];
        v += a2[o] * av;
        w += mlpw[o] * av;
    }
    vall[k] = v;
    wall[k] = w;
}

// per-node scalars ps,pd,qs,qd + fused x->bf16 conversion
__global__ __launch_bounds__(256) void k_node_scal(const float* __restrict__ x,
                                                   const float* __restrict__ vall,
                                                   const float* __restrict__ wall,
                                                   float* __restrict__ scal,
                                                   unsigned short* __restrict__ xb) {
    __shared__ float sv[1200];
    int tid = threadIdx.x;
    for (int i = tid; i < 1200; i += 256) sv[i] = (i < 600) ? vall[i] : wall[i - 600];
    __syncthreads();
    int lane = tid & 63;
    int n = blockIdx.x * 4 + (tid >> 6);
    float ps = 0.f, pd = 0.f, qs = 0.f, qd = 0.f;
    if (lane < 50) {
        float4 xv = *(const float4*)(x + (size_t)n * FDIM + lane * 4);
        float4 v1 = *(const float4*)(sv + lane * 4);
        float4 v2 = *(const float4*)(sv + 200 + lane * 4);
        float4 w1 = *(const float4*)(sv + 600 + lane * 4);
        float4 w2 = *(const float4*)(sv + 800 + lane * 4);
        ps = xv.x * v1.x + xv.y * v1.y + xv.z * v1.z + xv.w * v1.w;
        pd = xv.x * v2.x + xv.y * v2.y + xv.z * v2.z + xv.w * v2.w;
        qs = xv.x * w1.x + xv.y * w1.y + xv.z * w1.z + xv.w * w1.w;
        qd = xv.x * w2.x + xv.y * w2.y + xv.z * w2.z + xv.w * w2.w;
        ushort4 o;
        o.x = f2bf(xv.x); o.y = f2bf(xv.y); o.z = f2bf(xv.z); o.w = f2bf(xv.w);
        *(ushort4*)(xb + (size_t)n * FDIM + lane * 4) = o;
    }
    ps = wave_sum_bcast(ps);
    pd = wave_sum_bcast(pd);
    qs = wave_sum_bcast(qs);
    qd = wave_sum_bcast(qd);
    if (lane == 0) {
        float4 r = make_float4(ps, pd, qs, qd);
        *(float4*)(scal + (size_t)n * 4) = r;
    }
}

__global__ __launch_bounds__(256) void k_cvt(const float* __restrict__ src,
                                             unsigned short* __restrict__ dst, int n4) {
    int i = blockIdx.x * 256 + threadIdx.x;
    if (i >= n4) return;
    float4 v = *(const float4*)(src + (size_t)i * 4);
    ushort4 o;
    o.x = f2bf(v.x); o.y = f2bf(v.y); o.z = f2bf(v.z); o.w = f2bf(v.w);
    *(ushort4*)(dst + (size_t)i * 4) = o;
}

__global__ __launch_bounds__(256) void k_hist(const int* __restrict__ edge,
                                              const int* __restrict__ edgenh,
                                              int* __restrict__ counts) {
    int g = blockIdx.x * 256 + threadIdx.x;
    if (g >= EN) return;
    int s = (g < E1N) ? edge[g] : edgenh[g - E1N];
    atomicAdd(counts + s, 1);
}

__global__ __launch_bounds__(256) void k_scan1(const int* __restrict__ counts,
                                               int* __restrict__ incl,
                                               int* __restrict__ bsums) {
    __shared__ int tmp[256];
    int g = blockIdx.x * 256 + threadIdx.x;
    int v = (g < NN) ? counts[g] : 0;
    tmp[threadIdx.x] = v;
    __syncthreads();
    for (int off = 1; off < 256; off <<= 1) {
        int t = (threadIdx.x >= off) ? tmp[threadIdx.x - off] : 0;
        __syncthreads();
        tmp[threadIdx.x] += t;
        __syncthreads();
    }
    if (g < NN) incl[g] = tmp[threadIdx.x];
    if (threadIdx.x == 255) bsums[blockIdx.x] = tmp[255];
}

__global__ __launch_bounds__(256) void k_scan2(int* __restrict__ bsums, int nb) {
    __shared__ int tmp[256];
    int v = (threadIdx.x < nb) ? bsums[threadIdx.x] : 0;
    tmp[threadIdx.x] = v;
    __syncthreads();
    for (int off = 1; off < 256; off <<= 1) {
        int t = (threadIdx.x >= off) ? tmp[threadIdx.x - off] : 0;
        __syncthreads();
        tmp[threadIdx.x] += t;
        __syncthreads();
    }
    if (threadIdx.x < nb) bsums[threadIdx.x] = tmp[threadIdx.x] - v;  // exclusive
}

// incl -> exclusive offsets; also copy into fill (running cursor for scatter)
__global__ __launch_bounds__(256) void k_scan3(const int* __restrict__ counts,
                                               int* __restrict__ incl,
                                               const int* __restrict__ bsums,
                                               int* __restrict__ fill) {
    int g = blockIdx.x * 256 + threadIdx.x;
    if (g >= NN) return;
    int v = incl[g] - counts[g] + bsums[blockIdx.x];
    incl[g] = v;
    fill[g] = v;
}

// scatter (e, d, scal[d].y, scal[d].w) records grouped by src.
// scal is 0.8MB (L2-resident); gathering it HERE removes one dependent memory
// level from k_csr's per-node critical chain.
__global__ __launch_bounds__(256) void k_scatter(const int* __restrict__ edge,
                                                 const int* __restrict__ edgenh,
                                                 const float* __restrict__ scal,
                                                 int* __restrict__ fill,
                                                 int4* __restrict__ sorted4) {
    int g = blockIdx.x * 256 + threadIdx.x;
    if (g >= EN) return;
    int s, d;
    if (g < E1N) { s = edge[g]; d = edge[E1N + g]; }
    else { s = edgenh[g - E1N]; d = edgenh[E2N + (g - E1N)]; }
    float sy = scal[(size_t)d * 4 + 1];
    float sw = scal[(size_t)d * 4 + 3];
    int pos = atomicAdd(fill + s, 1);
    sorted4[pos] = make_int4(g, d, __float_as_int(sy), __float_as_int(sw));
}

// Fused per-node pass, latency-optimized:
//  - edge records (e, d, sdy, sdw) loaded LANE-PARALLEL per chunk of 60;
//    per-iteration access is a 1-cycle readlane (no dependent load chain)
//  - 6-slot modulo-scheduled row pipeline: ~5 rows (~6KB) in flight per wave
//  - chunk=60 keeps every pipeline index < 64 (readlane never wraps)
#define ISSUE(EV, XU, IDX) do {                                                   \
    int _e = __builtin_amdgcn_readlane(recx, (IDX));                              \
    int _d = __builtin_amdgcn_readlane(recy, (IDX));                              \
    const float* _er = (_e < E1N) ? ee + (size_t)_e * FDIM                        \
                                  : eenh + (size_t)(_e - E1N) * FDIM;             \
    if (lane < 50) {                                                              \
        EV = *(const float4*)(_er + lane * 4);                                    \
        XU = *(const ushort4*)(xb + (size_t)_d * FDIM + lane * 4);                \
    }                                                                             \
} while (0)

#define CONSUME(EV, XU, IDX) do {                                                 \
    float _pe = EV.x * v3.x + EV.y * v3.y + EV.z * v3.z + EV.w * v3.w;            \
    float _qe = EV.x * w3.x + EV.y * w3.y + EV.z * w3.z + EV.w * w3.w;            \
    _pe = wave_sum_bcast(_pe);                                                    \
    _qe = wave_sum_bcast(_qe);                                                    \
    float _sdy = readlane_f(sdy, (IDX));                                          \
    float _sdw = readlane_f(sdw, (IDX));                                          \
    float _z1 = scx + _sdy + _pe;                                                 \
    float _z2 = scz + _sdw + _qe + mb;                                            \
    float _l = _z1 > 0.f ? _z1 : 0.2f * _z1;                                      \
    float _e2 = __expf(2.f * _z2);                                                \
    float _t = 1.f - 2.f * __builtin_amdgcn_rcpf(_e2 + 1.f);                      \
    float _w = __expf(_l * _t * (-1.f / (float)EN));                              \
    _w = ((IDX) < m) ? _w : 0.f;                                                  \
    rs += _w;                                                                     \
    float _x0 = bf2f(XU.x), _x1 = bf2f(XU.y), _x2 = bf2f(XU.z), _x3 = bf2f(XU.w); \
    accx0 += _w * _x0; accx1 += _w * _x1; accx2 += _w * _x2; accx3 += _w * _x3;   \
    acce0 += _w * EV.x; acce1 += _w * EV.y; acce2 += _w * EV.z; acce3 += _w * EV.w; \
} while (0)

__global__ __launch_bounds__(256) void k_csr(const int4* __restrict__ sorted4,
                                             const int* __restrict__ offs,
                                             const int* __restrict__ counts,
                                             const float* __restrict__ ee,
                                             const float* __restrict__ eenh,
                                             const unsigned short* __restrict__ xb,
                                             const float* __restrict__ vall,
                                             const float* __restrict__ wall,
                                             const float* __restrict__ scal,
                                             const float* __restrict__ mlpb,
                                             float* __restrict__ rowsum,
                                             unsigned short* __restrict__ Tsb) {
    int tid = threadIdx.x, lane = tid & 63;
    int n = blockIdx.x * 4 + (tid >> 6);
    float4 v3 = make_float4(0, 0, 0, 0), w3 = v3;
    if (lane < 50) {
        v3 = *(const float4*)(vall + 400 + lane * 4);
        w3 = *(const float4*)(wall + 400 + lane * 4);
    }
    float scx = scal[(size_t)n * 4 + 0];
    float scz = scal[(size_t)n * 4 + 2];
    float mb = mlpb[0];
    int beg = offs[n], cnt = counts[n];
    float accx0 = 0, accx1 = 0, accx2 = 0, accx3 = 0;
    float acce0 = 0, acce1 = 0, acce2 = 0, acce3 = 0;
    float rs = 0.f;

    for (int c0 = 0; c0 < cnt; c0 += 60) {
        int m = cnt - c0; if (m > 60) m = 60;
        // lane-parallel edge-record gather for this chunk (single coalesced load)
        int recx = 0, recy = 0;
        float sdy = 0.f, sdw = 0.f;
        if (lane < m) {
            int4 rr = sorted4[beg + c0 + lane];
            recx = rr.x; recy = rr.y;
            sdy = __int_as_float(rr.z);
            sdw = __int_as_float(rr.w);
        }
        int m6 = ((m + 5) / 6) * 6;   // padded; CONSUME masks wgt for IDX >= m
        float4 ev0 = make_float4(0,0,0,0), ev1 = ev0, ev2 = ev0, ev3 = ev0, ev4 = ev0, ev5 = ev0;
        ushort4 xu0 = {0,0,0,0}, xu1 = xu0, xu2 = xu0, xu3 = xu0, xu4 = xu0, xu5 = xu0;
        // prologue: fill 6 slots (safe: masked-out lanes' rec = 0 -> valid row 0)
        ISSUE(ev0, xu0, 0);
        ISSUE(ev1, xu1, 1);
        ISSUE(ev2, xu2, 2);
        ISSUE(ev3, xu3, 3);
        ISSUE(ev4, xu4, 4);
        ISSUE(ev5, xu5, 5);
        for (int i = 0; i < m6; i += 6) {
            CONSUME(ev0, xu0, i + 0); if (i + 6  < m6) ISSUE(ev0, xu0, i + 6);
            CONSUME(ev1, xu1, i + 1); if (i + 7  < m6) ISSUE(ev1, xu1, i + 7);
            CONSUME(ev2, xu2, i + 2); if (i + 8  < m6) ISSUE(ev2, xu2, i + 8);
            CONSUME(ev3, xu3, i + 3); if (i + 9  < m6) ISSUE(ev3, xu3, i + 9);
            CONSUME(ev4, xu4, i + 4); if (i + 10 < m6) ISSUE(ev4, xu4, i + 10);
            CONSUME(ev5, xu5, i + 5); if (i + 11 < m6) ISSUE(ev5, xu5, i + 11);
        }
    }

    if (lane == 0) rowsum[n] = rs;
    float inv = (cnt > 0) ? __builtin_amdgcn_rcpf(rs) : 0.f;
    if (lane < 50) {
        ushort4 o1, o2;
        o1.x = f2bf(accx0 * inv); o1.y = f2bf(accx1 * inv);
        o1.z = f2bf(accx2 * inv); o1.w = f2bf(accx3 * inv);
        o2.x = f2bf(acce0 * inv); o2.y = f2bf(acce1 * inv);
        o2.z = f2bf(acce2 * inv); o2.w = f2bf(acce3 * inv);
        *(ushort4*)(Tsb + (size_t)n * 400 + lane * 4) = o1;
        *(ushort4*)(Tsb + (size_t)n * 400 + 200 + lane * 4) = o2;
    }
}

// single fused GEMM: out = elu([x | T/rs] @ A^T), rowsum==0 -> 0
// K padded to 640: [0,200) from xb, [224,624) from Tsb, rest zero. B from ab (stride 600).
// XCD-chunked block swizzle: grid 3128 = 8*391.
__global__ __launch_bounds__(256) void k_gemm_fused(const unsigned short* __restrict__ xb,
                                                    const unsigned short* __restrict__ tsb,
                                                    const unsigned short* __restrict__ ab,
                                                    const float* __restrict__ rowsum,
                                                    float* __restrict__ out) {
    __shared__ unsigned short Al[64][40];
    __shared__ unsigned short Bl[64][40];
    int tid = threadIdx.x, w = tid >> 6, lane = tid & 63;
    int h = blockIdx.y * 4 + blockIdx.x;          // linear hw id, x fastest
    int g = (h & 7) * 391 + (h >> 3);             // bijective: 3128 = 8*391
    int by = g >> 2, bx = g & 3;
    f32x4 acc[4] = {};
    int r = tid >> 2, c = tid & 3;
    int arow = by * 64 + r;
    int brow = bx * 64 + r;
    bool inA = arow < NN;
    bool inB = brow < 200;
    const unsigned short* aPx = xb + (size_t)arow * 200;
    const unsigned short* aPt = tsb + (size_t)arow * 400;
    const unsigned short* bP = ab + (size_t)brow * 600;
    for (int k0 = 0; k0 < 640; k0 += 32) {
        int gk = k0 + c * 8;
        uint4 av = make_uint4(0, 0, 0, 0), bv = av;
        if (gk < 200) {
            if (inA) av = *(const uint4*)(aPx + gk);
            if (inB) bv = *(const uint4*)(bP + gk);
        } else if (gk >= 224 && gk < 624) {
            if (inA) av = *(const uint4*)(aPt + (gk - 224));
            if (inB) bv = *(const uint4*)(bP + gk - 24);  // a col 200 + (gk-224)
        }
        *(uint4*)&Al[r][c * 8] = av;
        *(uint4*)&Bl[r][c * 8] = bv;
        __syncthreads();
        short8 af = *(short8*)&Al[w * 16 + (lane & 15)][(lane >> 4) * 8];
        #pragma unroll
        for (int ct = 0; ct < 4; ++ct) {
            short8 bf = *(short8*)&Bl[ct * 16 + (lane & 15)][(lane >> 4) * 8];
            acc[ct] = __builtin_amdgcn_mfma_f32_16x16x32_bf16(af, bf, acc[ct], 0, 0, 0);
        }
        __syncthreads();
    }
    #pragma unroll
    for (int ct = 0; ct < 4; ++ct) {
        #pragma unroll
        for (int rr = 0; rr < 4; ++rr) {
            int grow = by * 64 + w * 16 + (lane >> 4) * 4 + rr;
            int gcol = bx * 64 + ct * 16 + (lane & 15);
            if (grow < NN && gcol < 200) {
                float rsv = rowsum[grow];
                float hh = acc[ct][rr];
                float o = (rsv == 0.f) ? 0.f : (hh > 0.f ? hh : expm1f(hh));
                out[(size_t)grow * 200 + gcol] = o;
            }
        }
    }
}

extern "C" void kernel_launch(void* const* d_in, const int* in_sizes, int n_in,
                              void* d_out, int out_size, void* d_ws, size_t ws_size,
                              hipStream_t stream) {
    const float* x      = (const float*)d_in[0];
    const int*   edge   = (const int*)d_in[1];
    const float* ee     = (const float*)d_in[2];
    const int*   edgenh = (const int*)d_in[3];
    const float* eenh   = (const float*)d_in[4];
    const float* a      = (const float*)d_in[5];
    const float* a2     = (const float*)d_in[6];
    const float* mlpw   = (const float*)d_in[7];
    const float* mlpb   = (const float*)d_in[8];

    float* ws = (float*)d_ws;
    float* vall   = ws + VALL_OFF;
    float* wall   = ws + WALL_OFF;
    float* scal   = ws + SCAL_OFF;
    float* rowsum = ws + RS_OFF;
    int*   counts = (int*)(ws + CNT_OFF);
    int*   fill   = (int*)(ws + FILL_OFF);
    int*   incl   = (int*)(ws + INCL_OFF);
    int*   bsums  = (int*)(ws + BSUM_OFF);
    int4*  sorted4 = (int4*)(ws + SORT_OFF);
    unsigned short* xb  = (unsigned short*)(ws + XB_OFF);
    unsigned short* ab  = (unsigned short*)(ws + AB_OFF);
    unsigned short* tsb = (unsigned short*)(ws + TSB_OFF);

    hipMemsetAsync(counts, 0, (size_t)(2 * NN) * sizeof(int), stream);

    k_coeffs<<<3, 256, 0, stream>>>(a, a2, mlpw, vall, wall);
    k_node_scal<<<NN / 4, 256, 0, stream>>>(x, vall, wall, scal, xb);
    k_cvt<<<(200 * 600 / 4 + 255) / 256, 256, 0, stream>>>(a, ab, 200 * 600 / 4);

    k_hist<<<(EN + 255) / 256, 256, 0, stream>>>(edge, edgenh, counts);
    int nb = (NN + 255) / 256;
    k_scan1<<<nb, 256, 0, stream>>>(counts, incl, bsums);
    k_scan2<<<1, 256, 0, stream>>>(bsums, nb);
    k_scan3<<<nb, 256, 0, stream>>>(counts, incl, bsums, fill);
    k_scatter<<<(EN + 255) / 256, 256, 0, stream>>>(edge, edgenh, scal, fill, sorted4);

    k_csr<<<NN / 4, 256, 0, stream>>>(sorted4, incl, counts, ee, eenh, xb,
                                      vall, wall, scal, mlpb, rowsum, tsb);

    dim3 gg(4, (NN + 63) / 64);
    k_gemm_fused<<<gg, 256, 0, stream>>>(xb, tsb, ab, rowsum, (float*)d_out);
}

// Round 5
// 666.210 us; speedup vs baseline: 1.0361x; 1.0361x over previous
//
#include <hip/hip_runtime.h>
#include <math.h>

#define NN    50000
#define FDIM  200
#define E1N   400000
#define E2N   100000
#define EN    500000

typedef __attribute__((ext_vector_type(8))) short short8;
typedef __attribute__((ext_vector_type(4))) float f32x4;

// ---------------- workspace layout (4B units) ----------------
#define VALL_OFF   0            // 600 f
#define WALL_OFF   608          // 600 f
#define SCAL_OFF   1216         // NN*4 f = 200,000
#define RS_OFF     201216       // NN f
#define CNT_OFF    251216       // NN int (zeroed)
#define FILL_OFF   301216       // NN int (zeroed, then = offsets)
#define INCL_OFF   351216       // NN int (offsets)
#define BSUM_OFF   401216       // 256 int
#define SORT_OFF   401472       // EN int2 = 1,000,000 ints
#define XB_OFF     1401472      // NN*200 bf16 = 10,000,000 ushort = 5,000,000 f
#define AB_OFF     6401472      // 200*600 bf16 = 120,000 ushort = 60,000 f
#define TSB_OFF    6461472      // NN*400 bf16 = 20,000,000 ushort = 10,000,000 f
// total 16,461,472 floats = ~66 MB

static __device__ __forceinline__ unsigned short f2bf(float f) {
    unsigned int u = __float_as_uint(f);
    unsigned int r = (u + 0x7fffu + ((u >> 16) & 1u)) >> 16;
    return (unsigned short)r;
}
static __device__ __forceinline__ float bf2f(unsigned short s) {
    return __uint_as_float((unsigned int)s << 16);
}

// ---- DPP wave-64 sum (VALU-latency, 6 steps); result broadcast via readlane 63 ----
#define DPP_ADD(x, ctrl, rmask) \
    x += __int_as_float(__builtin_amdgcn_update_dpp(0, __float_as_int(x), ctrl, rmask, 0xf, true))

static __device__ __forceinline__ float wave_sum_bcast(float x) {
    DPP_ADD(x, 0x111, 0xf);   // row_shr:1
    DPP_ADD(x, 0x112, 0xf);   // row_shr:2
    DPP_ADD(x, 0x114, 0xf);   // row_shr:4
    DPP_ADD(x, 0x118, 0xf);   // row_shr:8
    DPP_ADD(x, 0x142, 0xa);   // row_bcast:15 -> rows 1,3
    DPP_ADD(x, 0x143, 0xc);   // row_bcast:31 -> rows 2,3
    return __int_as_float(__builtin_amdgcn_readlane(__float_as_int(x), 63));
}

static __device__ __forceinline__ float readlane_f(float v, int l) {
    return __int_as_float(__builtin_amdgcn_readlane(__float_as_int(v), l));
}

// ---- merged prep: hist + a->bf16 cvt + coeffs (independent; one launch) ----
#define HIST_BLOCKS 1954   // ceil(EN/256)
#define CVT_BLOCKS  118    // ceil(30000/256), 30000 = 200*600/4
__global__ __launch_bounds__(256) void k_prep(const float* __restrict__ a,
                                              const float* __restrict__ a2,
                                              const float* __restrict__ mlpw,
                                              const int* __restrict__ edge,
                                              const int* __restrict__ edgenh,
                                              float* __restrict__ vall,
                                              float* __restrict__ wall,
                                              unsigned short* __restrict__ ab,
                                              int* __restrict__ counts) {
    int b = blockIdx.x;
    if (b < HIST_BLOCKS) {
        int g = b * 256 + threadIdx.x;
        if (g < EN) {
            int s = (g < E1N) ? edge[g] : edgenh[g - E1N];
            atomicAdd(counts + s, 1);
        }
    } else if (b < HIST_BLOCKS + CVT_BLOCKS) {
        int i = (b - HIST_BLOCKS) * 256 + threadIdx.x;
        if (i < 30000) {
            float4 v = *(const float4*)(a + (size_t)i * 4);
            ushort4 o;
            o.x = f2bf(v.x); o.y = f2bf(v.y); o.z = f2bf(v.z); o.w = f2bf(v.w);
            *(ushort4*)(ab + (size_t)i * 4) = o;
        }
    } else {
        int k = (b - HIST_BLOCKS - CVT_BLOCKS) * 256 + threadIdx.x;
        if (k < 600) {
            float v = 0.f, w = 0.f;
            for (int o = 0; o < FDIM; ++o) {
                float av = a[o * 600 + k];
                v += a2[o] * av;
                w += mlpw[o] * av;
            }
            vall[k] = v;
            wall[k] = w;
        }
    }
}

// per-node scalars ps,pd,qs,qd + fused x->bf16 conversion
__global__ __launch_bounds__(256) void k_node_scal(const float* __restrict__ x,
                                                   const float* __restrict__ vall,
                                                   const float* __restrict__ wall,
                                                   float* __restrict__ scal,
                                                   unsigned short* __restrict__ xb) {
    __shared__ float sv[1200];
    int tid = threadIdx.x;
    for (int i = tid; i < 1200; i += 256) sv[i] = (i < 600) ? vall[i] : wall[i - 600];
    __syncthreads();
    int lane = tid & 63;
    int n = blockIdx.x * 4 + (tid >> 6);
    float ps = 0.f, pd = 0.f, qs = 0.f, qd = 0.f;
    if (lane < 50) {
        float4 xv = *(const float4*)(x + (size_t)n * FDIM + lane * 4);
        float4 v1 = *(const float4*)(sv + lane * 4);
        float4 v2 = *(const float4*)(sv + 200 + lane * 4);
        float4 w1 = *(const float4*)(sv + 600 + lane * 4);
        float4 w2 = *(const float4*)(sv + 800 + lane * 4);
        ps = xv.x * v1.x + xv.y * v1.y + xv.z * v1.z + xv.w * v1.w;
        pd = xv.x * v2.x + xv.y * v2.y + xv.z * v2.z + xv.w * v2.w;
        qs = xv.x * w1.x + xv.y * w1.y + xv.z * w1.z + xv.w * w1.w;
        qd = xv.x * w2.x + xv.y * w2.y + xv.z * w2.z + xv.w * w2.w;
        ushort4 o;
        o.x = f2bf(xv.x); o.y = f2bf(xv.y); o.z = f2bf(xv.z); o.w = f2bf(xv.w);
        *(ushort4*)(xb + (size_t)n * FDIM + lane * 4) = o;
    }
    ps = wave_sum_bcast(ps);
    pd = wave_sum_bcast(pd);
    qs = wave_sum_bcast(qs);
    qd = wave_sum_bcast(qd);
    if (lane == 0) {
        float4 r = make_float4(ps, pd, qs, qd);
        *(float4*)(scal + (size_t)n * 4) = r;
    }
}

__global__ __launch_bounds__(256) void k_scan1(const int* __restrict__ counts,
                                               int* __restrict__ incl,
                                               int* __restrict__ bsums) {
    __shared__ int tmp[256];
    int g = blockIdx.x * 256 + threadIdx.x;
    int v = (g < NN) ? counts[g] : 0;
    tmp[threadIdx.x] = v;
    __syncthreads();
    for (int off = 1; off < 256; off <<= 1) {
        int t = (threadIdx.x >= off) ? tmp[threadIdx.x - off] : 0;
        __syncthreads();
        tmp[threadIdx.x] += t;
        __syncthreads();
    }
    if (g < NN) incl[g] = tmp[threadIdx.x];
    if (threadIdx.x == 255) bsums[blockIdx.x] = tmp[255];
}

__global__ __launch_bounds__(256) void k_scan2(int* __restrict__ bsums, int nb) {
    __shared__ int tmp[256];
    int v = (threadIdx.x < nb) ? bsums[threadIdx.x] : 0;
    tmp[threadIdx.x] = v;
    __syncthreads();
    for (int off = 1; off < 256; off <<= 1) {
        int t = (threadIdx.x >= off) ? tmp[threadIdx.x - off] : 0;
        __syncthreads();
        tmp[threadIdx.x] += t;
        __syncthreads();
    }
    if (threadIdx.x < nb) bsums[threadIdx.x] = tmp[threadIdx.x] - v;  // exclusive
}

// incl -> exclusive offsets; also copy into fill (running cursor for scatter)
__global__ __launch_bounds__(256) void k_scan3(const int* __restrict__ counts,
                                               int* __restrict__ incl,
                                               const int* __restrict__ bsums,
                                               int* __restrict__ fill) {
    int g = blockIdx.x * 256 + threadIdx.x;
    if (g >= NN) return;
    int v = incl[g] - counts[g] + bsums[blockIdx.x];
    incl[g] = v;
    fill[g] = v;
}

// scatter (e, dst) pairs grouped by src
__global__ __launch_bounds__(256) void k_scatter(const int* __restrict__ edge,
                                                 const int* __restrict__ edgenh,
                                                 int* __restrict__ fill,
                                                 int2* __restrict__ sorted2) {
    int g = blockIdx.x * 256 + threadIdx.x;
    if (g >= EN) return;
    int s, d;
    if (g < E1N) { s = edge[g]; d = edge[E1N + g]; }
    else { s = edgenh[g - E1N]; d = edgenh[E2N + (g - E1N)]; }
    int pos = atomicAdd(fill + s, 1);
    sorted2[pos] = make_int2(g, d);
}

// Fused per-node pass (r3-proven structure):
//  - whole edge list + scal gathers loaded LANE-PARALLEL up front (chunks of 64)
//  - 4-slot modulo-scheduled row pipeline
//  - ee rows loaded NON-TEMPORAL (read-once 400MB; don't evict L3-resident xb/tsb)
#define ISSUE(EV, XU, IDX) do {                                                   \
    int _e = __builtin_amdgcn_readlane(recx, (IDX));                              \
    int _d = __builtin_amdgcn_readlane(recy, (IDX));                              \
    const float* _er = (_e < E1N) ? ee + (size_t)_e * FDIM                        \
                                  : eenh + (size_t)(_e - E1N) * FDIM;             \
    if (lane < 50) {                                                              \
        f32x4 _t = __builtin_nontemporal_load((const f32x4*)(_er + lane * 4));    \
        EV.x = _t.x; EV.y = _t.y; EV.z = _t.z; EV.w = _t.w;                       \
        XU = *(const ushort4*)(xb + (size_t)_d * FDIM + lane * 4);                \
    }                                                                             \
} while (0)

#define CONSUME(EV, XU, IDX) do {                                                 \
    float _pe = EV.x * v3.x + EV.y * v3.y + EV.z * v3.z + EV.w * v3.w;            \
    float _qe = EV.x * w3.x + EV.y * w3.y + EV.z * w3.z + EV.w * w3.w;            \
    _pe = wave_sum_bcast(_pe);                                                    \
    _qe = wave_sum_bcast(_qe);                                                    \
    float _sdy = readlane_f(sdy, (IDX));                                          \
    float _sdw = readlane_f(sdw, (IDX));                                          \
    float _z1 = scx + _sdy + _pe;                                                 \
    float _z2 = scz + _sdw + _qe + mb;                                            \
    float _l = _z1 > 0.f ? _z1 : 0.2f * _z1;                                      \
    float _e2 = __expf(2.f * _z2);                                                \
    float _t = 1.f - 2.f * __builtin_amdgcn_rcpf(_e2 + 1.f);                      \
    float _w = __expf(_l * _t * (-1.f / (float)EN));                              \
    _w = ((IDX) < m) ? _w : 0.f;                                                  \
    rs += _w;                                                                     \
    float _x0 = bf2f(XU.x), _x1 = bf2f(XU.y), _x2 = bf2f(XU.z), _x3 = bf2f(XU.w); \
    accx0 += _w * _x0; accx1 += _w * _x1; accx2 += _w * _x2; accx3 += _w * _x3;   \
    acce0 += _w * EV.x; acce1 += _w * EV.y; acce2 += _w * EV.z; acce3 += _w * EV.w; \
} while (0)

__global__ __launch_bounds__(256) void k_csr(const int2* __restrict__ sorted2,
                                             const int* __restrict__ offs,
                                             const int* __restrict__ counts,
                                             const float* __restrict__ ee,
                                             const float* __restrict__ eenh,
                                             const unsigned short* __restrict__ xb,
                                             const float* __restrict__ vall,
                                             const float* __restrict__ wall,
                                             const float* __restrict__ scal,
                                             const float* __restrict__ mlpb,
                                             float* __restrict__ rowsum,
                                             unsigned short* __restrict__ Tsb) {
    int tid = threadIdx.x, lane = tid & 63;
    int n = blockIdx.x * 4 + (tid >> 6);
    float4 v3 = make_float4(0, 0, 0, 0), w3 = v3;
    if (lane < 50) {
        v3 = *(const float4*)(vall + 400 + lane * 4);
        w3 = *(const float4*)(wall + 400 + lane * 4);
    }
    float scx = scal[(size_t)n * 4 + 0];
    float scz = scal[(size_t)n * 4 + 2];
    float mb = mlpb[0];
    int beg = offs[n], cnt = counts[n];
    float accx0 = 0, accx1 = 0, accx2 = 0, accx3 = 0;
    float acce0 = 0, acce1 = 0, acce2 = 0, acce3 = 0;
    float rs = 0.f;

    for (int c0 = 0; c0 < cnt; c0 += 64) {
        int m = cnt - c0; if (m > 64) m = 64;
        // lane-parallel edge-record + scal gather for this chunk
        int recx = 0, recy = 0;
        float sdy = 0.f, sdw = 0.f;
        if (lane < m) {
            int2 rr = sorted2[beg + c0 + lane];
            recx = rr.x; recy = rr.y;
            sdy = scal[(size_t)rr.y * 4 + 1];
            sdw = scal[(size_t)rr.y * 4 + 3];
        }
        int m4 = (m + 3) & ~3;   // padded; CONSUME masks wgt for IDX >= m
        float4 ev0 = make_float4(0,0,0,0), ev1 = ev0, ev2 = ev0, ev3 = ev0;
        ushort4 xu0 = {0,0,0,0}, xu1 = xu0, xu2 = xu0, xu3 = xu0;
        // prologue: fill 4 slots (m4 >= 4 whenever m >= 1)
        ISSUE(ev0, xu0, 0);
        ISSUE(ev1, xu1, 1);
        ISSUE(ev2, xu2, 2);
        ISSUE(ev3, xu3, 3);
        for (int i = 0; i < m4; i += 4) {
            CONSUME(ev0, xu0, i + 0); if (i + 4 < m4) ISSUE(ev0, xu0, i + 4);
            CONSUME(ev1, xu1, i + 1); if (i + 5 < m4) ISSUE(ev1, xu1, i + 5);
            CONSUME(ev2, xu2, i + 2); if (i + 6 < m4) ISSUE(ev2, xu2, i + 6);
            CONSUME(ev3, xu3, i + 3); if (i + 7 < m4) ISSUE(ev3, xu3, i + 7);
        }
    }

    if (lane == 0) rowsum[n] = rs;
    float inv = (cnt > 0) ? __builtin_amdgcn_rcpf(rs) : 0.f;
    if (lane < 50) {
        ushort4 o1, o2;
        o1.x = f2bf(accx0 * inv); o1.y = f2bf(accx1 * inv);
        o1.z = f2bf(accx2 * inv); o1.w = f2bf(accx3 * inv);
        o2.x = f2bf(acce0 * inv); o2.y = f2bf(acce1 * inv);
        o2.z = f2bf(acce2 * inv); o2.w = f2bf(acce3 * inv);
        *(ushort4*)(Tsb + (size_t)n * 400 + lane * 4) = o1;
        *(ushort4*)(Tsb + (size_t)n * 400 + 200 + lane * 4) = o2;
    }
}

// single fused GEMM: out = elu([x | T/rs] @ A^T), rowsum==0 -> 0
// 128x64 tile, 4 waves each owning 32 rows (2x 16-row MFMA frags x 4 col frags).
// K padded to 640: [0,200) from xb, [224,624) from Tsb. B from ab (stride 600).
// Bijective chunked XCD swizzle for nwg=1564: q=195, r=4.
#define GEMM_NWG 1564
__global__ __launch_bounds__(256) void k_gemm_fused(const unsigned short* __restrict__ xb,
                                                    const unsigned short* __restrict__ tsb,
                                                    const unsigned short* __restrict__ ab,
                                                    const float* __restrict__ rowsum,
                                                    float* __restrict__ out) {
    __shared__ unsigned short Al[128][40];
    __shared__ unsigned short Bl[64][40];
    int tid = threadIdx.x, w = tid >> 6, lane = tid & 63;
    int h = blockIdx.x;
    int xcd = h & 7, pos = h >> 3;               // q=195, r=4
    int g = (xcd < 4 ? xcd * 196 : 4 * 196 + (xcd - 4) * 195) + pos;
    int by = g >> 2, bx = g & 3;
    f32x4 acc[2][4] = {};
    int r = tid >> 2, c = tid & 3;
    int arow0 = by * 128 + r;
    int arow1 = arow0 + 64;
    int brow = bx * 64 + r;
    bool inA0 = arow0 < NN, inA1 = arow1 < NN;
    bool inB = brow < 200;
    const unsigned short* aPx0 = xb + (size_t)arow0 * 200;
    const unsigned short* aPt0 = tsb + (size_t)arow0 * 400;
    const unsigned short* aPx1 = xb + (size_t)arow1 * 200;
    const unsigned short* aPt1 = tsb + (size_t)arow1 * 400;
    const unsigned short* bP = ab + (size_t)brow * 600;
    for (int k0 = 0; k0 < 640; k0 += 32) {
        int gk = k0 + c * 8;
        uint4 av0 = make_uint4(0, 0, 0, 0), av1 = av0, bv = av0;
        if (gk < 200) {
            if (inA0) av0 = *(const uint4*)(aPx0 + gk);
            if (inA1) av1 = *(const uint4*)(aPx1 + gk);
            if (inB)  bv  = *(const uint4*)(bP + gk);
        } else if (gk >= 224 && gk < 624) {
            if (inA0) av0 = *(const uint4*)(aPt0 + (gk - 224));
            if (inA1) av1 = *(const uint4*)(aPt1 + (gk - 224));
            if (inB)  bv  = *(const uint4*)(bP + gk - 24);  // a col 200 + (gk-224)
        }
        *(uint4*)&Al[r][c * 8] = av0;
        *(uint4*)&Al[r + 64][c * 8] = av1;
        *(uint4*)&Bl[r][c * 8] = bv;
        __syncthreads();
        short8 af0 = *(short8*)&Al[w * 32 + (lane & 15)][(lane >> 4) * 8];
        short8 af1 = *(short8*)&Al[w * 32 + 16 + (lane & 15)][(lane >> 4) * 8];
        #pragma unroll
        for (int ct = 0; ct < 4; ++ct) {
            short8 bf = *(short8*)&Bl[ct * 16 + (lane & 15)][(lane >> 4) * 8];
            acc[0][ct] = __builtin_amdgcn_mfma_f32_16x16x32_bf16(af0, bf, acc[0][ct], 0, 0, 0);
            acc[1][ct] = __builtin_amdgcn_mfma_f32_16x16x32_bf16(af1, bf, acc[1][ct], 0, 0, 0);
        }
        __syncthreads();
    }
    #pragma unroll
    for (int m = 0; m < 2; ++m) {
        #pragma unroll
        for (int ct = 0; ct < 4; ++ct) {
            #pragma unroll
            for (int rr = 0; rr < 4; ++rr) {
                int grow = by * 128 + w * 32 + m * 16 + (lane >> 4) * 4 + rr;
                int gcol = bx * 64 + ct * 16 + (lane & 15);
                if (grow < NN && gcol < 200) {
                    float rsv = rowsum[grow];
                    float hh = acc[m][ct][rr];
                    float o = (rsv == 0.f) ? 0.f : (hh > 0.f ? hh : expm1f(hh));
                    out[(size_t)grow * 200 + gcol] = o;
                }
            }
        }
    }
}

extern "C" void kernel_launch(void* const* d_in, const int* in_sizes, int n_in,
                              void* d_out, int out_size, void* d_ws, size_t ws_size,
                              hipStream_t stream) {
    const float* x      = (const float*)d_in[0];
    const int*   edge   = (const int*)d_in[1];
    const float* ee     = (const float*)d_in[2];
    const int*   edgenh = (const int*)d_in[3];
    const float* eenh   = (const float*)d_in[4];
    const float* a      = (const float*)d_in[5];
    const float* a2     = (const float*)d_in[6];
    const float* mlpw   = (const float*)d_in[7];
    const float* mlpb   = (const float*)d_in[8];

    float* ws = (float*)d_ws;
    float* vall   = ws + VALL_OFF;
    float* wall   = ws + WALL_OFF;
    float* scal   = ws + SCAL_OFF;
    float* rowsum = ws + RS_OFF;
    int*   counts = (int*)(ws + CNT_OFF);
    int*   fill   = (int*)(ws + FILL_OFF);
    int*   incl   = (int*)(ws + INCL_OFF);
    int*   bsums  = (int*)(ws + BSUM_OFF);
    int2*  sorted2 = (int2*)(ws + SORT_OFF);
    unsigned short* xb  = (unsigned short*)(ws + XB_OFF);
    unsigned short* ab  = (unsigned short*)(ws + AB_OFF);
    unsigned short* tsb = (unsigned short*)(ws + TSB_OFF);

    hipMemsetAsync(counts, 0, (size_t)(2 * NN) * sizeof(int), stream);

    k_prep<<<HIST_BLOCKS + CVT_BLOCKS + 3, 256, 0, stream>>>(a, a2, mlpw, edge, edgenh,
                                                             vall, wall, ab, counts);
    k_node_scal<<<NN / 4, 256, 0, stream>>>(x, vall, wall, scal, xb);

    int nb = (NN + 255) / 256;
    k_scan1<<<nb, 256, 0, stream>>>(counts, incl, bsums);
    k_scan2<<<1, 256, 0, stream>>>(bsums, nb);
    k_scan3<<<nb, 256, 0, stream>>>(counts, incl, bsums, fill);
    k_scatter<<<(EN + 255) / 256, 256, 0, stream>>>(edge, edgenh, fill, sorted2);

    k_csr<<<NN / 4, 256, 0, stream>>>(sorted2, incl, counts, ee, eenh, xb,
                                      vall, wall, scal, mlpb, rowsum, tsb);

    k_gemm_fused<<<GEMM_NWG, 256, 0, stream>>>(xb, tsb, ab, rowsum, (float*)d_out);
}